// Round 8
// baseline (755.674 us; speedup 1.0000x reference)
//
#include <hip/hip_runtime.h>
#include <hip/hip_bf16.h>
#include <math.h>

#define E_EDGES 1000000
#define LN_EPS  1e-5f

typedef unsigned short u16;
typedef __bf16 bf16x8 __attribute__((ext_vector_type(8)));
typedef float  f32x16 __attribute__((ext_vector_type(16)));
typedef unsigned uv4 __attribute__((ext_vector_type(4)));

__device__ __forceinline__ float lo2f(unsigned d) {
    union { unsigned u; float f; } v; v.u = d << 16; return v.f;
}
__device__ __forceinline__ float hi2f(unsigned d) {
    union { unsigned u; float f; } v; v.u = d & 0xffff0000u; return v.f;
}
__device__ __forceinline__ unsigned pk2(float lo, float hi) {
    __hip_bfloat162 h = __float22bfloat162_rn(make_float2(lo, hi));
    unsigned r; __builtin_memcpy(&r, &h, 4); return r;
}
// non-temporal 16B store: don't allocate output streams in L2/L3 (keeps the
// gather working set resident in Infinity Cache -> this is the experiment).
__device__ __forceinline__ void nt_store16(void* p, uint4 v) {
    uv4 w; __builtin_memcpy(&w, &v, 16);
    __builtin_nontemporal_store(w, (uv4*)p);
}

// ---------------------------------------------------------------------------
// Weight -> bf16 MFMA B-fragment conversion (one-time, ~128 KB in d_out;
// head_mfma overwrites d_out afterwards).
// slot s = (ks*2+nt)*64 + l holds B[k=ks*16+(l>>5)*8+j][n=nt*32+(l&31)].
// ---------------------------------------------------------------------------
__global__ __launch_bounds__(256) void wconv_kernel(
    const float* __restrict__ wr, const float* __restrict__ w0,
    u16* __restrict__ wf)
{
    const int s = blockIdx.x * 256 + threadIdx.x;   // 0..8191
    const int l    = s & 63;
    const int nt   = (s >> 6) & 1;
    const int col  = nt * 32 + (l & 31);
    const int half = l >> 5;
    uint4 pk;
    if (s < 3 * 2560) {
        const int L  = s / 2560;
        const int sl = s % 2560;
        const int kb = (sl >> 7) * 16 + half * 8;
        const float* W = wr + L * 320 * 64;
        pk.x = pk2(W[(kb+0)*64+col], W[(kb+1)*64+col]);
        pk.y = pk2(W[(kb+2)*64+col], W[(kb+3)*64+col]);
        pk.z = pk2(W[(kb+4)*64+col], W[(kb+5)*64+col]);
        pk.w = pk2(W[(kb+6)*64+col], W[(kb+7)*64+col]);
    } else {
        const int sl = s - 3 * 2560;
        const int kb = (sl >> 7) * 16 + half * 8;
        float v[8];
        #pragma unroll
        for (int p = 0; p < 8; ++p) v[p] = (kb + p < 55) ? w0[(kb+p)*64 + col] : 0.f;
        pk.x = pk2(v[0],v[1]); pk.y = pk2(v[2],v[3]);
        pk.z = pk2(v[4],v[5]); pk.w = pk2(v[6],v[7]);
    }
    *(uint4*)&wf[(size_t)s * 8] = pk;
}

// ---------------------------------------------------------------------------
// Layers 1..3: feats(E x 320) @ W + b -> LN -> ReLU -> +residual.
// 64 edges/block, 4 waves = (mt,nt), afrag 40 KB -> 4 blocks/CU.
// Bank swizzle granule ^= (kstep&3); residual kept in registers;
// xout written with NT stores (cache-bypass) to protect L3 residency of xin.
// ---------------------------------------------------------------------------
__global__ __launch_bounds__(256, 4) void layer_mfma(
    const u16* __restrict__ xin, const int* __restrict__ nbr,
    const u16* __restrict__ wf, const float* __restrict__ bias,
    const float* __restrict__ lng, const float* __restrict__ lnb,
    u16* __restrict__ xout)
{
    __shared__ u16 afrag[2 * 20 * 64 * 8];   // 40 KB
    const int t  = threadIdx.x;
    const int l  = t & 63;
    const int wv = t >> 6;
    const int e0 = blockIdx.x * 64;          // grid exact: 15625*64 = 1e6
    const int el = t >> 2;                   // 0..63 local edge
    const int cq = t & 3;                    // 16-ch quarter

    // hoisted LN params for this thread's channel slice [cq*16, cq*16+16)
    float lgv[16], lbv[16];
    #pragma unroll
    for (int j = 0; j < 4; ++j) {
        *(float4*)&lgv[j * 4] = *(const float4*)(lng + cq * 16 + j * 4);
        *(float4*)&lbv[j * 4] = *(const float4*)(lnb + cq * 16 + j * 4);
    }

    uint4 xv0, xv1;                          // own row: features + residual
    {
        const size_t e = (size_t)(e0 + el);
        const int4 n = *(const int4*)(nbr + 4 * e);
        const u16* xr = xin + e * 64           + cq * 16;
        const u16* ar = xin + (size_t)n.x * 64 + cq * 16;
        const u16* br = xin + (size_t)n.y * 64 + cq * 16;
        const u16* cr = xin + (size_t)n.z * 64 + cq * 16;
        const u16* dr = xin + (size_t)n.w * 64 + cq * 16;
        xv0 = *(const uint4*)(xr);                 xv1 = *(const uint4*)(xr + 8);
        const uint4 av0 = *(const uint4*)(ar);     const uint4 av1 = *(const uint4*)(ar + 8);
        const uint4 bv0 = *(const uint4*)(br);     const uint4 bv1 = *(const uint4*)(br + 8);
        const uint4 cv0 = *(const uint4*)(cr);     const uint4 cv1 = *(const uint4*)(cr + 8);
        const uint4 dv0 = *(const uint4*)(dr);     const uint4 dv1 = *(const uint4*)(dr + 8);
        const int mt_g  = el >> 5;
        const int lane0 = el & 31;
        u16* abase = afrag + (size_t)mt_g * (20 * 64 * 8);
        #pragma unroll
        for (int w8 = 0; w8 < 2; ++w8) {
            const uint4 xv = w8 ? xv1 : xv0;
            const uint4 av = w8 ? av1 : av0;
            const uint4 bv = w8 ? bv1 : bv0;
            const uint4 cv = w8 ? cv1 : cv0;
            const uint4 dv = w8 ? dv1 : dv0;
            const int gsw = (lane0 + 32 * w8) ^ cq;   // bank swizzle
            uint4 g1, g2, g3, g4;
            const unsigned* ap = (const unsigned*)&av;
            const unsigned* bp = (const unsigned*)&bv;
            const unsigned* cp = (const unsigned*)&cv;
            const unsigned* dp = (const unsigned*)&dv;
            unsigned* g1p = (unsigned*)&g1; unsigned* g2p = (unsigned*)&g2;
            unsigned* g3p = (unsigned*)&g3; unsigned* g4p = (unsigned*)&g4;
            #pragma unroll
            for (int i = 0; i < 4; ++i) {
                const float a0 = lo2f(ap[i]), a1 = hi2f(ap[i]);
                const float c0 = lo2f(cp[i]), c1 = hi2f(cp[i]);
                g1p[i] = pk2(a0 - c0, a1 - c1) & 0x7FFF7FFFu;   // |RNE(x)|=RNE(|x|)
                g2p[i] = pk2(a0 + c0, a1 + c1);
                const float b0 = lo2f(bp[i]), b1 = hi2f(bp[i]);
                const float d0 = lo2f(dp[i]), d1 = hi2f(dp[i]);
                g3p[i] = pk2(b0 - d0, b1 - d1) & 0x7FFF7FFFu;
                g4p[i] = pk2(b0 + d0, b1 + d1);
            }
            // group g -> row (kstep) = g*4 + cq; row&3 == cq matches read swizzle
            *(uint4*)(abase + (size_t)(((0*4 + cq) * 64) + gsw) * 8) = xv;
            *(uint4*)(abase + (size_t)(((1*4 + cq) * 64) + gsw) * 8) = g1;
            *(uint4*)(abase + (size_t)(((2*4 + cq) * 64) + gsw) * 8) = g2;
            *(uint4*)(abase + (size_t)(((3*4 + cq) * 64) + gsw) * 8) = g3;
            *(uint4*)(abase + (size_t)(((4*4 + cq) * 64) + gsw) * 8) = g4;
        }
    }
    __syncthreads();

    // ---- K-loop: 20 ksteps; A from LDS (swizzled), B from global frags ----
    const int mt = wv >> 1, nt = wv & 1;
    f32x16 acc = {};
    const u16* ab = afrag + (size_t)mt * (20 * 512);
    const u16* bb = wf + (size_t)(nt * 64 + l) * 8;
    #pragma unroll
    for (int ks = 0; ks < 20; ++ks) {
        const bf16x8 a8 = *(const bf16x8*)(ab + (size_t)(ks * 64 + (l ^ (ks & 3))) * 8);
        const bf16x8 b8 = *(const bf16x8*)(bb + ks * 1024);
        acc = __builtin_amdgcn_mfma_f32_32x32x16_bf16(a8, b8, acc, 0, 0, 0);
    }
    __syncthreads();

    // ---- epilogue: C + bias -> ebuf [64][68] (aliases afrag) ----
    float* ebuf = (float*)afrag;
    {
        const int col  = nt * 32 + (l & 31);
        const int quad = l >> 5;
        const float bc = bias[col];
        #pragma unroll
        for (int r = 0; r < 16; ++r) {
            const int row = mt * 32 + (r & 3) + 8 * (r >> 2) + 4 * quad;
            ebuf[row * 68 + col] = acc[r] + bc;
        }
    }
    __syncthreads();

    // ---- LN + ReLU + residual(regs) -> bf16 NT store (4 threads/edge) ----
    {
        const float* rp = ebuf + el * 68 + cq * 16;
        float v[16];
        float s = 0.f, qs = 0.f;
        #pragma unroll
        for (int i = 0; i < 16; ++i) { v[i] = rp[i]; s += v[i]; qs += v[i] * v[i]; }
        s  += __shfl_xor(s, 1);  s  += __shfl_xor(s, 2);
        qs += __shfl_xor(qs, 1); qs += __shfl_xor(qs, 2);
        const float mu   = s * (1.f / 64.f);
        const float var  = qs * (1.f / 64.f) - mu * mu;
        const float rinv = rsqrtf(var + LN_EPS);
        const size_t e   = (size_t)(e0 + el);
        u16* outp        = xout + e * 64 + cq * 16;
        #pragma unroll
        for (int h = 0; h < 2; ++h) {
            const uint4 res = h ? xv1 : xv0;           // residual from registers
            const unsigned* rr = (const unsigned*)&res;
            uint4 o; unsigned* op = (unsigned*)&o;
            #pragma unroll
            for (int i = 0; i < 4; ++i) {
                const int k = h * 8 + i * 2;
                const float y0 = fmaxf(fmaf((v[k]     - mu) * rinv, lgv[k],     lbv[k]),     0.f) + lo2f(rr[i]);
                const float y1 = fmaxf(fmaf((v[k + 1] - mu) * rinv, lgv[k + 1], lbv[k + 1]), 0.f) + hi2f(rr[i]);
                op[i] = pk2(y0, y1);
            }
            nt_store16(outp + h * 8, o);
        }
    }
}

// ---------------------------------------------------------------------------
// Layer 0 (MFMA, K padded 55->64): 64 edges/block, 4 waves, 17.4 KB LDS.
// Thread (el, cq) builds k-range [cq*16, cq*16+16) of the concat features.
// ---------------------------------------------------------------------------
__global__ __launch_bounds__(256, 6) void layer0_mfma(
    const float* __restrict__ x, const int* __restrict__ nbr,
    const u16* __restrict__ wf0, const float* __restrict__ bias,
    const float* __restrict__ lng, const float* __restrict__ lnb,
    u16* __restrict__ xout)
{
    __shared__ float smem[64 * 68];          // 17.4 KB; first 8 KB doubles as afrag
    u16* afrag = (u16*)smem;
    const int t  = threadIdx.x;
    const int l  = t & 63;
    const int wv = t >> 6;
    const int e0 = blockIdx.x * 64;          // grid exact: 15625
    const int el = t >> 2, cq = t & 3;

    {
        const size_t e = (size_t)(e0 + el);
        const int4 n = *(const int4*)(nbr + 4 * e);
        const float* xr = x + e * 11;
        const float* ar = x + (size_t)n.x * 11;
        const float* br = x + (size_t)n.y * 11;
        const float* cr = x + (size_t)n.z * 11;
        const float* dr = x + (size_t)n.w * 11;
        float f[16];
        if (cq == 0) {            // k 0..10: x ; k 11..15: |a-c|[0..4]
            #pragma unroll
            for (int i = 0; i < 11; ++i) f[i] = xr[i];
            #pragma unroll
            for (int i = 0; i < 5; ++i) f[11 + i] = fabsf(ar[i] - cr[i]);
        } else if (cq == 1) {     // k 16..21: |a-c|[5..10] ; k 22..31: a+c[0..9]
            #pragma unroll
            for (int i = 0; i < 6; ++i) f[i] = fabsf(ar[5 + i] - cr[5 + i]);
            #pragma unroll
            for (int i = 0; i < 10; ++i) f[6 + i] = ar[i] + cr[i];
        } else if (cq == 2) {     // k32: a+c[10]; k33..43: |b-d|; k44..47: b+d[0..3]
            f[0] = ar[10] + cr[10];
            #pragma unroll
            for (int i = 0; i < 11; ++i) f[1 + i] = fabsf(br[i] - dr[i]);
            #pragma unroll
            for (int i = 0; i < 4; ++i) f[12 + i] = br[i] + dr[i];
        } else {                  // k48..54: b+d[4..10]; k55..63: pad 0
            #pragma unroll
            for (int i = 0; i < 7; ++i) f[i] = br[4 + i] + dr[4 + i];
            #pragma unroll
            for (int i = 7; i < 16; ++i) f[i] = 0.f;
        }
        const int mt_g  = el >> 5;
        const int lane0 = el & 31;
        u16* abase = afrag + (size_t)mt_g * (4 * 64 * 8);
        #pragma unroll
        for (int hh = 0; hh < 2; ++hh) {
            uint4 pk;
            pk.x = pk2(f[hh*8+0], f[hh*8+1]);
            pk.y = pk2(f[hh*8+2], f[hh*8+3]);
            pk.z = pk2(f[hh*8+4], f[hh*8+5]);
            pk.w = pk2(f[hh*8+6], f[hh*8+7]);
            const int gsw = (lane0 + 32 * hh) ^ cq;   // row (=cq) bank swizzle
            *(uint4*)(abase + (size_t)(cq * 64 + gsw) * 8) = pk;
        }
    }
    __syncthreads();

    const int mt = wv >> 1, nt = wv & 1;
    f32x16 acc = {};
    const u16* ab = afrag + (size_t)mt * (4 * 512);
    const u16* bb = wf0 + (size_t)(nt * 64 + l) * 8;
    #pragma unroll
    for (int ks = 0; ks < 4; ++ks) {
        const bf16x8 a8 = *(const bf16x8*)(ab + (size_t)(ks * 64 + (l ^ ks)) * 8);
        const bf16x8 b8 = *(const bf16x8*)(bb + ks * 1024);
        acc = __builtin_amdgcn_mfma_f32_32x32x16_bf16(a8, b8, acc, 0, 0, 0);
    }
    __syncthreads();

    float* ebuf = smem;
    {
        const int col  = nt * 32 + (l & 31);
        const int quad = l >> 5;
        const float bc = bias[col];
        #pragma unroll
        for (int r = 0; r < 16; ++r) {
            const int row = mt * 32 + (r & 3) + 8 * (r >> 2) + 4 * quad;
            ebuf[row * 68 + col] = acc[r] + bc;
        }
    }
    __syncthreads();

    {
        const float* rp = ebuf + el * 68 + cq * 16;
        float v[16];
        float s = 0.f, qs = 0.f;
        #pragma unroll
        for (int i = 0; i < 16; ++i) { v[i] = rp[i]; s += v[i]; qs += v[i] * v[i]; }
        s  += __shfl_xor(s, 1);  s  += __shfl_xor(s, 2);
        qs += __shfl_xor(qs, 1); qs += __shfl_xor(qs, 2);
        const float mu   = s * (1.f / 64.f);
        const float var  = qs * (1.f / 64.f) - mu * mu;
        const float rinv = rsqrtf(var + LN_EPS);
        const size_t e   = (size_t)(e0 + el);
        u16* outp        = xout + e * 64 + cq * 16;
        #pragma unroll
        for (int h = 0; h < 2; ++h) {
            uint4 o; unsigned* op = (unsigned*)&o;
            #pragma unroll
            for (int i = 0; i < 4; ++i) {
                const int ci = cq * 16 + h * 8 + i * 2;
                const float y0 = fmaxf(fmaf((v[h*8 + i*2]     - mu) * rinv, lng[ci],     lnb[ci]),     0.f);
                const float y1 = fmaxf(fmaf((v[h*8 + i*2 + 1] - mu) * rinv, lng[ci + 1], lnb[ci + 1]), 0.f);
                op[i] = pk2(y0, y1);
            }
            nt_store16(outp + h * 8, o);
        }
    }
}

// ---------------------------------------------------------------------------
// Head (MFMA): logits = relu(x @ cw1 + cb1) @ cw2 + cb2.
// One 32-edge tile per wave; row-sum via per-wave LDS transpose.
// ---------------------------------------------------------------------------
__global__ __launch_bounds__(256) void head_mfma(
    const u16* __restrict__ xin,
    const float* __restrict__ cw1, const float* __restrict__ cb1,
    const float* __restrict__ cw2, const float* __restrict__ cb2,
    float* __restrict__ out)
{
    __shared__ float hbuf[4][32 * 33];
    const int t    = threadIdx.x;
    const int l    = t & 63;
    const int wv   = t >> 6;
    const int col  = l & 31;
    const int half = l >> 5;

    bf16x8 bf[4];
    #pragma unroll
    for (int ks = 0; ks < 4; ++ks) {
        const int kb = ks * 16 + half * 8;
        uint4 pk;
        pk.x = pk2(cw1[(kb+0)*32 + col], cw1[(kb+1)*32 + col]);
        pk.y = pk2(cw1[(kb+2)*32 + col], cw1[(kb+3)*32 + col]);
        pk.z = pk2(cw1[(kb+4)*32 + col], cw1[(kb+5)*32 + col]);
        pk.w = pk2(cw1[(kb+6)*32 + col], cw1[(kb+7)*32 + col]);
        __builtin_memcpy(&bf[ks], &pk, 16);
    }
    const float bc = cb1[col];
    const float w2 = cw2[col];
    const float b2 = cb2[0];

    int tile = blockIdx.x * 4 + wv;
    const int valid = tile < (E_EDGES / 32);
    if (!valid) tile = E_EDGES / 32 - 1;
    const size_t e0 = (size_t)tile * 32;
    const u16* xb = xin + (e0 + col) * 64 + half * 8;
    f32x16 acc = {};
    #pragma unroll
    for (int ks = 0; ks < 4; ++ks) {
        const bf16x8 a8 = *(const bf16x8*)(xb + ks * 16);
        acc = __builtin_amdgcn_mfma_f32_32x32x16_bf16(a8, bf[ks], acc, 0, 0, 0);
    }
    float* hb = hbuf[wv];
    #pragma unroll
    for (int r = 0; r < 16; ++r) {
        const int row = (r & 3) + 8 * (r >> 2) + 4 * half;
        hb[row * 33 + col] = fmaxf(acc[r] + bc, 0.f) * w2;
    }
    __syncthreads();
    const int row2 = l >> 1, part = l & 1;
    const float* rp = hb + row2 * 33 + part * 16;
    float s = 0.f;
    #pragma unroll
    for (int i = 0; i < 16; ++i) s += rp[i];
    s += __shfl_xor(s, 1);
    if (valid && part == 0) out[e0 + row2] = s + b2;
}

// ---------------------------------------------------------------------------
extern "C" void kernel_launch(void* const* d_in, const int* in_sizes, int n_in,
                              void* d_out, int out_size, void* d_ws, size_t ws_size,
                              hipStream_t stream)
{
    (void)in_sizes; (void)n_in; (void)out_size; (void)ws_size;
    const float* x   = (const float*)d_in[0];
    const int*   nbr = (const int*)d_in[1];
    const float* w0  = (const float*)d_in[2];
    const float* b0  = (const float*)d_in[3];
    const float* wr  = (const float*)d_in[4];
    const float* br  = (const float*)d_in[5];
    const float* lg  = (const float*)d_in[6];
    const float* lb  = (const float*)d_in[7];
    const float* cw1 = (const float*)d_in[8];
    const float* cb1 = (const float*)d_in[9];
    const float* cw2 = (const float*)d_in[10];
    const float* cb2 = (const float*)d_in[11];
    float* out = (float*)d_out;

    u16* xa = (u16*)d_ws;                       // E x 64 bf16 (128 MB)
    u16* xb = xa + (size_t)E_EDGES * 64;        // E x 64 bf16 (128 MB)
    u16* wfrag = (u16*)d_out;                   // 128 KB scratch; head overwrites d_out

    const dim3 blk(256);

    wconv_kernel<<<dim3(32), blk, 0, stream>>>(wr, w0, wfrag);
    layer0_mfma<<<dim3(E_EDGES / 64), blk, 0, stream>>>(x, nbr, wfrag + 3*20480, b0, lg, lb, xa);
    layer_mfma<<<dim3(E_EDGES / 64), blk, 0, stream>>>(xa, nbr, wfrag,           br,        lg + 64,  lb + 64,  xb);
    layer_mfma<<<dim3(E_EDGES / 64), blk, 0, stream>>>(xb, nbr, wfrag + 20480,   br + 64,   lg + 128, lb + 128, xa);
    layer_mfma<<<dim3(E_EDGES / 64), blk, 0, stream>>>(xa, nbr, wfrag + 40960,   br + 128,  lg + 192, lb + 192, xb);
    head_mfma<<<dim3((E_EDGES / 32 + 3) / 4), blk, 0, stream>>>(xb, cw1, cb1, cw2, cb2, out);
}

// Round 9
// 644.842 us; speedup vs baseline: 1.1719x; 1.1719x over previous
//
#include <hip/hip_runtime.h>
#include <hip/hip_bf16.h>
#include <math.h>

#define E_EDGES 1000000
#define LN_EPS  1e-5f

typedef unsigned short u16;
typedef __bf16 bf16x8 __attribute__((ext_vector_type(8)));
typedef float  f32x16 __attribute__((ext_vector_type(16)));

__device__ __forceinline__ float lo2f(unsigned d) {
    union { unsigned u; float f; } v; v.u = d << 16; return v.f;
}
__device__ __forceinline__ float hi2f(unsigned d) {
    union { unsigned u; float f; } v; v.u = d & 0xffff0000u; return v.f;
}
__device__ __forceinline__ float bf2f(u16 u) {
    union { unsigned u; float f; } v; v.u = ((unsigned)u) << 16; return v.f;
}
__device__ __forceinline__ unsigned pk2(float lo, float hi) {
    __hip_bfloat162 h = __float22bfloat162_rn(make_float2(lo, hi));
    unsigned r; __builtin_memcpy(&r, &h, 4); return r;
}

// ---------------------------------------------------------------------------
// Weight -> bf16 MFMA B-fragment conversion (one-time, ~132 KB).
// slots 0..7679: layers 1..3 (ks*2+nt)*64+l ; 7680..8191: layer0 (K pad 64);
// 8192..8447: cw1 (K=64, N=32) for the fused head.
// ---------------------------------------------------------------------------
__global__ __launch_bounds__(256) void wconv_kernel(
    const float* __restrict__ wr, const float* __restrict__ w0,
    const float* __restrict__ cw1, u16* __restrict__ wf)
{
    const int s = blockIdx.x * 256 + threadIdx.x;   // 0..8447
    if (s >= 8448) return;
    const int l    = s & 63;
    const int half = l >> 5;
    uint4 pk;
    if (s < 3 * 2560) {
        const int col = ((s >> 6) & 1) * 32 + (l & 31);
        const int L  = s / 2560;
        const int sl = s % 2560;
        const int kb = (sl >> 7) * 16 + half * 8;
        const float* W = wr + L * 320 * 64;
        pk.x = pk2(W[(kb+0)*64+col], W[(kb+1)*64+col]);
        pk.y = pk2(W[(kb+2)*64+col], W[(kb+3)*64+col]);
        pk.z = pk2(W[(kb+4)*64+col], W[(kb+5)*64+col]);
        pk.w = pk2(W[(kb+6)*64+col], W[(kb+7)*64+col]);
    } else if (s < 8192) {
        const int col = ((s >> 6) & 1) * 32 + (l & 31);
        const int sl = s - 3 * 2560;
        const int kb = (sl >> 7) * 16 + half * 8;
        float v[8];
        #pragma unroll
        for (int p = 0; p < 8; ++p) v[p] = (kb + p < 55) ? w0[(kb+p)*64 + col] : 0.f;
        pk.x = pk2(v[0],v[1]); pk.y = pk2(v[2],v[3]);
        pk.z = pk2(v[4],v[5]); pk.w = pk2(v[6],v[7]);
    } else {                                         // cw1 frags (N=32)
        const int sl = s - 8192;                     // 0..255
        const int ks = sl >> 6;
        const int col = l & 31;
        const int kb = ks * 16 + half * 8;
        pk.x = pk2(cw1[(kb+0)*32+col], cw1[(kb+1)*32+col]);
        pk.y = pk2(cw1[(kb+2)*32+col], cw1[(kb+3)*32+col]);
        pk.z = pk2(cw1[(kb+4)*32+col], cw1[(kb+5)*32+col]);
        pk.w = pk2(cw1[(kb+6)*32+col], cw1[(kb+7)*32+col]);
    }
    *(uint4*)&wf[(size_t)s * 8] = pk;
}

// ---------------------------------------------------------------------------
// xprep: x fp32[E][11] (44 B rows, line-crossing) -> xc bf16[E][16]
// (32 B rows, aligned). Makes layer0's gather 4 aligned 32-B requests/edge.
// ---------------------------------------------------------------------------
__global__ __launch_bounds__(256) void xprep_kernel(
    const float* __restrict__ x, u16* __restrict__ xc)
{
    __shared__ float xs[2816];                  // 256 edges * 11 floats
    const int t = threadIdx.x;
    const long long i0 = (long long)blockIdx.x * 704;   // float4 base
    #pragma unroll
    for (int k = 0; k < 3; ++k) {
        const int idx = t + k * 256;
        if (idx < 704 && i0 + idx < 2750000)
            *(float4*)&xs[idx * 4] = ((const float4*)x)[i0 + idx];
    }
    __syncthreads();
    const size_t e = (size_t)blockIdx.x * 256 + t;
    if (e < E_EDGES) {
        const float* r = &xs[t * 11];
        uint4 o0, o1;
        o0.x = pk2(r[0], r[1]);  o0.y = pk2(r[2], r[3]);
        o0.z = pk2(r[4], r[5]);  o0.w = pk2(r[6], r[7]);
        o1.x = pk2(r[8], r[9]);  o1.y = pk2(r[10], 0.f);
        o1.z = 0u;               o1.w = 0u;
        *(uint4*)&xc[e * 16]     = o0;
        *(uint4*)&xc[e * 16 + 8] = o1;
    }
}

// ---------------------------------------------------------------------------
// Layer 0 (MFMA, K pad 55->64): gather 32-B compact rows -> LDS raw ->
// feature build -> afrag -> GEMM -> LN -> ReLU.
// ---------------------------------------------------------------------------
__global__ __launch_bounds__(256, 4) void layer0_mfma(
    const u16* __restrict__ xc, const int* __restrict__ nbr,
    const u16* __restrict__ wf0, const float* __restrict__ bias,
    const float* __restrict__ lng, const float* __restrict__ lnb,
    u16* __restrict__ xout)
{
    __shared__ float smem[64 * 68];          // 17.4 KB; first 8 KB = afrag
    __shared__ u16  raw[64 * 5 * 16];        // 10 KB: [edge][slot 0=own,1..4=n]
    u16* afrag = (u16*)smem;
    const int t  = threadIdx.x;
    const int l  = t & 63;
    const int wv = t >> 6;
    const int e0 = blockIdx.x * 64;          // grid exact: 15625
    const int el = t >> 2, cq = t & 3;

    {   // ---- gather: 4 threads/edge, thread j loads neighbor row j ----
        const size_t e = (size_t)(e0 + el);
        const int4 n = *(const int4*)(nbr + 4 * e);
        const int nj = (cq == 0) ? n.x : (cq == 1) ? n.y : (cq == 2) ? n.z : n.w;
        const u16* nr = xc + (size_t)nj * 16;
        u16* dst = raw + (el * 5 + 1 + cq) * 16;
        *(uint4*)dst       = *(const uint4*)nr;
        *(uint4*)(dst + 8) = *(const uint4*)(nr + 8);
        if (cq == 0) {
            const u16* xr = xc + e * 16;
            u16* od = raw + (el * 5) * 16;
            *(uint4*)od       = *(const uint4*)xr;
            *(uint4*)(od + 8) = *(const uint4*)(xr + 8);
        }
    }
    __syncthreads();

    {   // ---- feature build: thread (el,cq) owns k-range [cq*16, cq*16+16) ----
        const u16* R = raw + el * 5 * 16;
        // slots: 0=own x, 1=a(n0), 2=b(n1), 3=c(n2), 4=d(n3)
        float f[16];
        if (cq == 0) {            // k0..10: x ; k11..15: |a-c|[0..4]
            #pragma unroll
            for (int i = 0; i < 11; ++i) f[i] = bf2f(R[i]);
            #pragma unroll
            for (int i = 0; i < 5; ++i) f[11+i] = fabsf(bf2f(R[16+i]) - bf2f(R[48+i]));
        } else if (cq == 1) {     // k16..21: |a-c|[5..10] ; k22..31: a+c[0..9]
            #pragma unroll
            for (int i = 0; i < 6; ++i) f[i] = fabsf(bf2f(R[16+5+i]) - bf2f(R[48+5+i]));
            #pragma unroll
            for (int i = 0; i < 10; ++i) f[6+i] = bf2f(R[16+i]) + bf2f(R[48+i]);
        } else if (cq == 2) {     // k32: a+c[10]; k33..43: |b-d|; k44..47: b+d[0..3]
            f[0] = bf2f(R[16+10]) + bf2f(R[48+10]);
            #pragma unroll
            for (int i = 0; i < 11; ++i) f[1+i] = fabsf(bf2f(R[32+i]) - bf2f(R[64+i]));
            #pragma unroll
            for (int i = 0; i < 4; ++i) f[12+i] = bf2f(R[32+i]) + bf2f(R[64+i]);
        } else {                  // k48..54: b+d[4..10]; pad
            #pragma unroll
            for (int i = 0; i < 7; ++i) f[i] = bf2f(R[32+4+i]) + bf2f(R[64+4+i]);
            #pragma unroll
            for (int i = 7; i < 16; ++i) f[i] = 0.f;
        }
        const int mt_g  = el >> 5;
        const int lane0 = el & 31;
        u16* abase = afrag + (size_t)mt_g * (4 * 64 * 8);
        #pragma unroll
        for (int hh = 0; hh < 2; ++hh) {
            uint4 pk;
            pk.x = pk2(f[hh*8+0], f[hh*8+1]);
            pk.y = pk2(f[hh*8+2], f[hh*8+3]);
            pk.z = pk2(f[hh*8+4], f[hh*8+5]);
            pk.w = pk2(f[hh*8+6], f[hh*8+7]);
            const int gsw = (lane0 + 32 * hh) ^ cq;   // row(=cq) bank swizzle
            *(uint4*)(abase + (size_t)(cq * 64 + gsw) * 8) = pk;
        }
    }
    __syncthreads();

    const int mt = wv >> 1, nt = wv & 1;
    f32x16 acc = {};
    const u16* ab = afrag + (size_t)mt * (4 * 512);
    const u16* bb = wf0 + (size_t)(nt * 64 + l) * 8;
    #pragma unroll
    for (int ks = 0; ks < 4; ++ks) {
        const bf16x8 a8 = *(const bf16x8*)(ab + (size_t)(ks * 64 + (l ^ ks)) * 8);
        const bf16x8 b8 = *(const bf16x8*)(bb + ks * 1024);
        acc = __builtin_amdgcn_mfma_f32_32x32x16_bf16(a8, b8, acc, 0, 0, 0);
    }
    __syncthreads();

    float* ebuf = smem;
    {
        const int col  = nt * 32 + (l & 31);
        const int quad = l >> 5;
        const float bc = bias[col];
        #pragma unroll
        for (int r = 0; r < 16; ++r) {
            const int row = mt * 32 + (r & 3) + 8 * (r >> 2) + 4 * quad;
            ebuf[row * 68 + col] = acc[r] + bc;
        }
    }
    __syncthreads();

    {
        const float* rp = ebuf + el * 68 + cq * 16;
        float v[16];
        float s = 0.f, qs = 0.f;
        #pragma unroll
        for (int i = 0; i < 16; ++i) { v[i] = rp[i]; s += v[i]; qs += v[i] * v[i]; }
        s  += __shfl_xor(s, 1);  s  += __shfl_xor(s, 2);
        qs += __shfl_xor(qs, 1); qs += __shfl_xor(qs, 2);
        const float mu   = s * (1.f / 64.f);
        const float var  = qs * (1.f / 64.f) - mu * mu;
        const float rinv = rsqrtf(var + LN_EPS);
        const size_t e   = (size_t)(e0 + el);
        u16* outp        = xout + e * 64 + cq * 16;
        #pragma unroll
        for (int h = 0; h < 2; ++h) {
            uint4 o; unsigned* op = (unsigned*)&o;
            #pragma unroll
            for (int i = 0; i < 4; ++i) {
                const int ci = cq * 16 + h * 8 + i * 2;
                const float y0 = fmaxf(fmaf((v[h*8+i*2]   - mu) * rinv, lng[ci],   lnb[ci]),   0.f);
                const float y1 = fmaxf(fmaf((v[h*8+i*2+1] - mu) * rinv, lng[ci+1], lnb[ci+1]), 0.f);
                op[i] = pk2(y0, y1);
            }
            *(uint4*)(outp + h * 8) = o;
        }
    }
}

// ---------------------------------------------------------------------------
// Common gather+pack for layers 1..3 (R6 structure, plain stores).
// ---------------------------------------------------------------------------
__device__ __forceinline__ void layer_gather_pack(
    const u16* __restrict__ xin, const int* __restrict__ nbr,
    u16* __restrict__ afrag, int e0, int el, int cq, uint4& xv0, uint4& xv1)
{
    const size_t e = (size_t)(e0 + el);
    const int4 n = *(const int4*)(nbr + 4 * e);
    const u16* xr = xin + e * 64           + cq * 16;
    const u16* ar = xin + (size_t)n.x * 64 + cq * 16;
    const u16* br = xin + (size_t)n.y * 64 + cq * 16;
    const u16* cr = xin + (size_t)n.z * 64 + cq * 16;
    const u16* dr = xin + (size_t)n.w * 64 + cq * 16;
    xv0 = *(const uint4*)(xr);                 xv1 = *(const uint4*)(xr + 8);
    const uint4 av0 = *(const uint4*)(ar);     const uint4 av1 = *(const uint4*)(ar + 8);
    const uint4 bv0 = *(const uint4*)(br);     const uint4 bv1 = *(const uint4*)(br + 8);
    const uint4 cv0 = *(const uint4*)(cr);     const uint4 cv1 = *(const uint4*)(cr + 8);
    const uint4 dv0 = *(const uint4*)(dr);     const uint4 dv1 = *(const uint4*)(dr + 8);
    const int mt_g  = el >> 5;
    const int lane0 = el & 31;
    u16* abase = afrag + (size_t)mt_g * (20 * 64 * 8);
    #pragma unroll
    for (int w8 = 0; w8 < 2; ++w8) {
        const uint4 xv = w8 ? xv1 : xv0;
        const uint4 av = w8 ? av1 : av0;
        const uint4 bv = w8 ? bv1 : bv0;
        const uint4 cv = w8 ? cv1 : cv0;
        const uint4 dv = w8 ? dv1 : dv0;
        const int gsw = (lane0 + 32 * w8) ^ cq;
        uint4 g1, g2, g3, g4;
        const unsigned* ap = (const unsigned*)&av;
        const unsigned* bp = (const unsigned*)&bv;
        const unsigned* cp = (const unsigned*)&cv;
        const unsigned* dp = (const unsigned*)&dv;
        unsigned* g1p = (unsigned*)&g1; unsigned* g2p = (unsigned*)&g2;
        unsigned* g3p = (unsigned*)&g3; unsigned* g4p = (unsigned*)&g4;
        #pragma unroll
        for (int i = 0; i < 4; ++i) {
            const float a0 = lo2f(ap[i]), a1 = hi2f(ap[i]);
            const float c0 = lo2f(cp[i]), c1 = hi2f(cp[i]);
            g1p[i] = pk2(a0 - c0, a1 - c1) & 0x7FFF7FFFu;
            g2p[i] = pk2(a0 + c0, a1 + c1);
            const float b0 = lo2f(bp[i]), b1 = hi2f(bp[i]);
            const float d0 = lo2f(dp[i]), d1 = hi2f(dp[i]);
            g3p[i] = pk2(b0 - d0, b1 - d1) & 0x7FFF7FFFu;
            g4p[i] = pk2(b0 + d0, b1 + d1);
        }
        *(uint4*)(abase + (size_t)(((0*4 + cq) * 64) + gsw) * 8) = xv;
        *(uint4*)(abase + (size_t)(((1*4 + cq) * 64) + gsw) * 8) = g1;
        *(uint4*)(abase + (size_t)(((2*4 + cq) * 64) + gsw) * 8) = g2;
        *(uint4*)(abase + (size_t)(((3*4 + cq) * 64) + gsw) * 8) = g3;
        *(uint4*)(abase + (size_t)(((4*4 + cq) * 64) + gsw) * 8) = g4;
    }
}

// ---------------------------------------------------------------------------
// Layers 1..2 (and 3 in fallback): GEMM -> LN -> ReLU -> +res -> store.
// ---------------------------------------------------------------------------
__global__ __launch_bounds__(256, 4) void layer_mfma(
    const u16* __restrict__ xin, const int* __restrict__ nbr,
    const u16* __restrict__ wf, const float* __restrict__ bias,
    const float* __restrict__ lng, const float* __restrict__ lnb,
    u16* __restrict__ xout)
{
    __shared__ u16 afrag[2 * 20 * 64 * 8];   // 40 KB
    const int t  = threadIdx.x;
    const int l  = t & 63;
    const int wv = t >> 6;
    const int e0 = blockIdx.x * 64;
    const int el = t >> 2;
    const int cq = t & 3;

    float lgv[16], lbv[16];
    #pragma unroll
    for (int j = 0; j < 4; ++j) {
        *(float4*)&lgv[j * 4] = *(const float4*)(lng + cq * 16 + j * 4);
        *(float4*)&lbv[j * 4] = *(const float4*)(lnb + cq * 16 + j * 4);
    }

    uint4 xv0, xv1;
    layer_gather_pack(xin, nbr, afrag, e0, el, cq, xv0, xv1);
    __syncthreads();

    const int mt = wv >> 1, nt = wv & 1;
    f32x16 acc = {};
    const u16* ab = afrag + (size_t)mt * (20 * 512);
    const u16* bb = wf + (size_t)(nt * 64 + l) * 8;
    #pragma unroll
    for (int ks = 0; ks < 20; ++ks) {
        const bf16x8 a8 = *(const bf16x8*)(ab + (size_t)(ks * 64 + (l ^ (ks & 3))) * 8);
        const bf16x8 b8 = *(const bf16x8*)(bb + ks * 1024);
        acc = __builtin_amdgcn_mfma_f32_32x32x16_bf16(a8, b8, acc, 0, 0, 0);
    }
    __syncthreads();

    float* ebuf = (float*)afrag;
    {
        const int col  = nt * 32 + (l & 31);
        const int quad = l >> 5;
        const float bc = bias[col];
        #pragma unroll
        for (int r = 0; r < 16; ++r) {
            const int row = mt * 32 + (r & 3) + 8 * (r >> 2) + 4 * quad;
            ebuf[row * 68 + col] = acc[r] + bc;
        }
    }
    __syncthreads();

    {
        const float* rp = ebuf + el * 68 + cq * 16;
        float v[16];
        float s = 0.f, qs = 0.f;
        #pragma unroll
        for (int i = 0; i < 16; ++i) { v[i] = rp[i]; s += v[i]; qs += v[i] * v[i]; }
        s  += __shfl_xor(s, 1);  s  += __shfl_xor(s, 2);
        qs += __shfl_xor(qs, 1); qs += __shfl_xor(qs, 2);
        const float mu   = s * (1.f / 64.f);
        const float var  = qs * (1.f / 64.f) - mu * mu;
        const float rinv = rsqrtf(var + LN_EPS);
        const size_t e   = (size_t)(e0 + el);
        u16* outp        = xout + e * 64 + cq * 16;
        #pragma unroll
        for (int h = 0; h < 2; ++h) {
            const uint4 res = h ? xv1 : xv0;
            const unsigned* rr = (const unsigned*)&res;
            uint4 o; unsigned* op = (unsigned*)&o;
            #pragma unroll
            for (int i = 0; i < 4; ++i) {
                const int k = h * 8 + i * 2;
                const float y0 = fmaxf(fmaf((v[k]   - mu) * rinv, lgv[k],   lbv[k]),   0.f) + lo2f(rr[i]);
                const float y1 = fmaxf(fmaf((v[k+1] - mu) * rinv, lgv[k+1], lbv[k+1]), 0.f) + hi2f(rr[i]);
                op[i] = pk2(y0, y1);
            }
            *(uint4*)(outp + h * 8) = o;
        }
    }
}

// ---------------------------------------------------------------------------
// Layer 3 fused with head: y = relu(LN(h))+x -> logits = relu(y@cw1+cb1)@cw2+cb2.
// y never goes to HBM; second GEMM reads y-frags from LDS (region inside afrag).
// ---------------------------------------------------------------------------
__global__ __launch_bounds__(256, 4) void layer_head_mfma(
    const u16* __restrict__ xin, const int* __restrict__ nbr,
    const u16* __restrict__ wf, const float* __restrict__ bias,
    const float* __restrict__ lng, const float* __restrict__ lnb,
    const u16* __restrict__ wfh, const float* __restrict__ cb1,
    const float* __restrict__ cw2, const float* __restrict__ cb2,
    float* __restrict__ out)
{
    __shared__ u16 afrag[2 * 20 * 64 * 8];   // 40 KB; carved: ebuf/ybuf/hbuf2
    u16*   ybuf  = afrag + 9216;             // bytes 18432..26624 (4096 u16)
    float* hbuf2 = (float*)(afrag + 14336);  // bytes 28672..37120 (2112 f32)
    const int t  = threadIdx.x;
    const int l  = t & 63;
    const int wv = t >> 6;
    const int e0 = blockIdx.x * 64;
    const int el = t >> 2;
    const int cq = t & 3;

    float lgv[16], lbv[16];
    #pragma unroll
    for (int j = 0; j < 4; ++j) {
        *(float4*)&lgv[j * 4] = *(const float4*)(lng + cq * 16 + j * 4);
        *(float4*)&lbv[j * 4] = *(const float4*)(lnb + cq * 16 + j * 4);
    }

    uint4 xv0, xv1;
    layer_gather_pack(xin, nbr, afrag, e0, el, cq, xv0, xv1);
    __syncthreads();

    const int mt = wv >> 1, nt = wv & 1;
    f32x16 acc = {};
    {
        const u16* ab = afrag + (size_t)mt * (20 * 512);
        const u16* bb = wf + (size_t)(nt * 64 + l) * 8;
        #pragma unroll
        for (int ks = 0; ks < 20; ++ks) {
            const bf16x8 a8 = *(const bf16x8*)(ab + (size_t)(ks * 64 + (l ^ (ks & 3))) * 8);
            const bf16x8 b8 = *(const bf16x8*)(bb + ks * 1024);
            acc = __builtin_amdgcn_mfma_f32_32x32x16_bf16(a8, b8, acc, 0, 0, 0);
        }
    }
    __syncthreads();

    float* ebuf = (float*)afrag;             // bytes 0..17408
    {
        const int col  = nt * 32 + (l & 31);
        const int quad = l >> 5;
        const float bc = bias[col];
        #pragma unroll
        for (int r = 0; r < 16; ++r) {
            const int row = mt * 32 + (r & 3) + 8 * (r >> 2) + 4 * quad;
            ebuf[row * 68 + col] = acc[r] + bc;
        }
    }
    __syncthreads();

    {   // LN + ReLU + residual -> y (bf16) -> ybuf in A-frag layout
        const float* rp = ebuf + el * 68 + cq * 16;
        float v[16];
        float s = 0.f, qs = 0.f;
        #pragma unroll
        for (int i = 0; i < 16; ++i) { v[i] = rp[i]; s += v[i]; qs += v[i] * v[i]; }
        s  += __shfl_xor(s, 1);  s  += __shfl_xor(s, 2);
        qs += __shfl_xor(qs, 1); qs += __shfl_xor(qs, 2);
        const float mu   = s * (1.f / 64.f);
        const float var  = qs * (1.f / 64.f) - mu * mu;
        const float rinv = rsqrtf(var + LN_EPS);
        const int mt_g  = el >> 5;
        const int lane0 = el & 31;
        #pragma unroll
        for (int h = 0; h < 2; ++h) {
            const uint4 res = h ? xv1 : xv0;
            const unsigned* rr = (const unsigned*)&res;
            uint4 o; unsigned* op = (unsigned*)&o;
            #pragma unroll
            for (int i = 0; i < 4; ++i) {
                const int k = h * 8 + i * 2;
                const float y0 = fmaxf(fmaf((v[k]   - mu) * rinv, lgv[k],   lbv[k]),   0.f) + lo2f(rr[i]);
                const float y1 = fmaxf(fmaf((v[k+1] - mu) * rinv, lgv[k+1], lbv[k+1]), 0.f) + hi2f(rr[i]);
                op[i] = pk2(y0, y1);
            }
            const int gsw = (lane0 + 32 * h) ^ cq;   // bank swizzle (row=cq)
            *(uint4*)(ybuf + (size_t)(((mt_g * 4 + cq) * 64) + gsw) * 8) = o;
        }
    }
    __syncthreads();

    // ---- GEMM2: y(64x64) @ cw1(64x32), waves 0..1 (mt2 = wv) ----
    if (wv < 2) {
        const int mt2 = wv;
        f32x16 a2 = {};
        #pragma unroll
        for (int ks = 0; ks < 4; ++ks) {
            const bf16x8 a8 = *(const bf16x8*)(ybuf + (size_t)(((mt2 * 4 + ks) * 64) + (l ^ ks)) * 8);
            const bf16x8 b8 = *(const bf16x8*)(wfh + (size_t)(ks * 64 + l) * 8);
            a2 = __builtin_amdgcn_mfma_f32_32x32x16_bf16(a8, b8, a2, 0, 0, 0);
        }
        const int col = l & 31;
        const float bc1 = cb1[col];
        const float w2v = cw2[col];
        float* hb = hbuf2 + mt2 * (32 * 33);
        #pragma unroll
        for (int r = 0; r < 16; ++r) {
            const int row = (r & 3) + 8 * (r >> 2) + 4 * (l >> 5);
            hb[row * 33 + col] = fmaxf(a2[r] + bc1, 0.f) * w2v;
        }
    }
    __syncthreads();

    // ---- row-sum -> logits ----
    if (t < 128) {
        const int edge = t >> 1, part = t & 1;
        const float* rp = hbuf2 + (edge >> 5) * (32 * 33) + (edge & 31) * 33 + part * 16;
        float s = 0.f;
        #pragma unroll
        for (int i = 0; i < 16; ++i) s += rp[i];
        s += __shfl_xor(s, 1);
        if (part == 0) out[e0 + edge] = s + cb2[0];
    }
}

// ---------------------------------------------------------------------------
// Standalone head (fallback path when workspace can't hold W-frags).
// ---------------------------------------------------------------------------
__global__ __launch_bounds__(256) void head_mfma(
    const u16* __restrict__ xin,
    const float* __restrict__ cw1, const float* __restrict__ cb1,
    const float* __restrict__ cw2, const float* __restrict__ cb2,
    float* __restrict__ out)
{
    __shared__ float hbuf[4][32 * 33];
    const int t    = threadIdx.x;
    const int l    = t & 63;
    const int wv   = t >> 6;
    const int col  = l & 31;
    const int half = l >> 5;

    bf16x8 bf[4];
    #pragma unroll
    for (int ks = 0; ks < 4; ++ks) {
        const int kb = ks * 16 + half * 8;
        uint4 pk;
        pk.x = pk2(cw1[(kb+0)*32 + col], cw1[(kb+1)*32 + col]);
        pk.y = pk2(cw1[(kb+2)*32 + col], cw1[(kb+3)*32 + col]);
        pk.z = pk2(cw1[(kb+4)*32 + col], cw1[(kb+5)*32 + col]);
        pk.w = pk2(cw1[(kb+6)*32 + col], cw1[(kb+7)*32 + col]);
        __builtin_memcpy(&bf[ks], &pk, 16);
    }
    const float bc = cb1[col];
    const float w2 = cw2[col];
    const float b2 = cb2[0];

    int tile = blockIdx.x * 4 + wv;
    const int valid = tile < (E_EDGES / 32);
    if (!valid) tile = E_EDGES / 32 - 1;
    const size_t e0 = (size_t)tile * 32;
    const u16* xb = xin + (e0 + col) * 64 + half * 8;
    f32x16 acc = {};
    #pragma unroll
    for (int ks = 0; ks < 4; ++ks) {
        const bf16x8 a8 = *(const bf16x8*)(xb + ks * 16);
        acc = __builtin_amdgcn_mfma_f32_32x32x16_bf16(a8, bf[ks], acc, 0, 0, 0);
    }
    float* hb = hbuf[wv];
    #pragma unroll
    for (int r = 0; r < 16; ++r) {
        const int row = (r & 3) + 8 * (r >> 2) + 4 * half;
        hb[row * 33 + col] = fmaxf(acc[r] + bc, 0.f) * w2;
    }
    __syncthreads();
    const int row2 = l >> 1, part = l & 1;
    const float* rp = hb + row2 * 33 + part * 16;
    float s = 0.f;
    #pragma unroll
    for (int i = 0; i < 16; ++i) s += rp[i];
    s += __shfl_xor(s, 1);
    if (valid && part == 0) out[e0 + row2] = s + b2;
}

// ---------------------------------------------------------------------------
extern "C" void kernel_launch(void* const* d_in, const int* in_sizes, int n_in,
                              void* d_out, int out_size, void* d_ws, size_t ws_size,
                              hipStream_t stream)
{
    (void)in_sizes; (void)n_in; (void)out_size;
    const float* x   = (const float*)d_in[0];
    const int*   nbr = (const int*)d_in[1];
    const float* w0  = (const float*)d_in[2];
    const float* b0  = (const float*)d_in[3];
    const float* wr  = (const float*)d_in[4];
    const float* br  = (const float*)d_in[5];
    const float* lg  = (const float*)d_in[6];
    const float* lb  = (const float*)d_in[7];
    const float* cw1 = (const float*)d_in[8];
    const float* cb1 = (const float*)d_in[9];
    const float* cw2 = (const float*)d_in[10];
    const float* cb2 = (const float*)d_in[11];
    float* out = (float*)d_out;

    u16* xa = (u16*)d_ws;                         // E*64 bf16 = 128e6 B
    u16* xb = xa + (size_t)E_EDGES * 64;          // E*64 bf16 = 128e6 B
    u16* xc = xb;                                 // 32 MB, dead until layer1 writes xb

    const size_t act_bytes = 2ull * E_EDGES * 64 * 2;        // 256e6
    const size_t wf_bytes  = 8448ull * 16;                   // 135168
    const bool fused = (ws_size >= act_bytes + wf_bytes);
    u16* wfrag = fused ? (u16*)((char*)d_ws + act_bytes) : (u16*)d_out;

    const dim3 blk(256);
    wconv_kernel<<<dim3(33), blk, 0, stream>>>(wr, w0, cw1, wfrag);
    xprep_kernel<<<dim3((E_EDGES + 255) / 256), blk, 0, stream>>>(x, xc);
    layer0_mfma<<<dim3(E_EDGES / 64), blk, 0, stream>>>(xc, nbr, wfrag + 3*20480, b0, lg, lb, xa);
    layer_mfma<<<dim3(E_EDGES / 64), blk, 0, stream>>>(xa, nbr, wfrag,         br,       lg + 64,  lb + 64,  xb);
    layer_mfma<<<dim3(E_EDGES / 64), blk, 0, stream>>>(xb, nbr, wfrag + 20480, br + 64,  lg + 128, lb + 128, xa);
    if (fused) {
        layer_head_mfma<<<dim3(E_EDGES / 64), blk, 0, stream>>>(
            xa, nbr, wfrag + 40960, br + 128, lg + 192, lb + 192,
            wfrag + 65536, cb1, cw2, cb2, out);
    } else {
        layer_mfma<<<dim3(E_EDGES / 64), blk, 0, stream>>>(xa, nbr, wfrag + 40960,
            br + 128, lg + 192, lb + 192, xb);
        head_mfma<<<dim3((E_EDGES / 32 + 3) / 4), blk, 0, stream>>>(xb, cw1, cb1, cw2, cb2, out);
    }
}